// Round 17
// baseline (458.871 us; speedup 1.0000x reference)
//
#include <hip/hip_runtime.h>
#include <math.h>

#define NT 256

typedef unsigned short ushort_t;
typedef unsigned int uint_t;

__device__ __forceinline__ float rlf(float v, int l) {
    return __int_as_float(__builtin_amdgcn_readlane(__float_as_int(v), l));
}
__device__ __forceinline__ int rli(int v, int l) {
    return __builtin_amdgcn_readlane(v, l);
}
__device__ __forceinline__ int imax(int a, int b) { return a > b ? a : b; }

__device__ __forceinline__ ushort_t f2bf_rne(float f) {
    uint_t u = __float_as_uint(f);
    uint_t r = u + 0x7FFF + ((u >> 16) & 1);
    return (ushort_t)(r >> 16);
}
__device__ __forceinline__ float bf2f(ushort_t b) {
    return __uint_as_float(((uint_t)b) << 16);
}

// ---------------- CSR build ----------------

__global__ void zero_i32(int* __restrict__ p, int n) {
    int t = blockIdx.x * blockDim.x + threadIdx.x;
    if (t < n) p[t] = 0;
}

__global__ void hist_dst(int* __restrict__ cnt, const int* __restrict__ dst, int n_edges) {
    int e = blockIdx.x * blockDim.x + threadIdx.x;
    if (e < n_edges) atomicAdd(&cnt[dst[e]], 1);
}

// ---- parallel 3-kernel exclusive scan of cnt[0..n) (r13-proven) ----
__global__ void scan_blocks(const int* __restrict__ cnt, int* __restrict__ bsum, int n) {
    __shared__ int s[NT];
    int i = blockIdx.x * NT + threadIdx.x;
    s[threadIdx.x] = (i < n) ? cnt[i] : 0;
    __syncthreads();
    for (int off = NT / 2; off > 0; off >>= 1) {
        if (threadIdx.x < off) s[threadIdx.x] += s[threadIdx.x + off];
        __syncthreads();
    }
    if (threadIdx.x == 0) bsum[blockIdx.x] = s[0];
}

__global__ void scan_bsum(const int* __restrict__ bsum, int* __restrict__ boff,
                          int nb, int* __restrict__ row_off, int n) {
    __shared__ int s[1024];
    int tid = threadIdx.x;
    int v = (tid < nb) ? bsum[tid] : 0;
    s[tid] = v;
    __syncthreads();
    for (int off = 1; off < 1024; off <<= 1) {
        int t = (tid >= off) ? s[tid - off] : 0;
        __syncthreads();
        s[tid] += t;
        __syncthreads();
    }
    if (tid < nb) boff[tid] = s[tid] - v;
    if (tid == nb - 1) row_off[n] = s[tid];
}

__global__ void scan_final(const int* __restrict__ cnt, const int* __restrict__ boff,
                           int* __restrict__ row_off, int* __restrict__ cursor, int n) {
    __shared__ int s[NT];
    int i = blockIdx.x * NT + threadIdx.x;
    int v = (i < n) ? cnt[i] : 0;
    s[threadIdx.x] = v;
    __syncthreads();
    for (int off = 1; off < NT; off <<= 1) {
        int t = (threadIdx.x >= off) ? s[threadIdx.x - off] : 0;
        __syncthreads();
        s[threadIdx.x] += t;
        __syncthreads();
    }
    if (i < n) {
        int ex = boff[blockIdx.x] + s[threadIdx.x] - v;
        row_off[i] = ex;
        cursor[i] = ex;
    }
}

__global__ void edge_scatter(int* __restrict__ csr_src, int* __restrict__ cursor,
                             const int* __restrict__ src, const int* __restrict__ dst,
                             int n_edges) {
    int e = blockIdx.x * blockDim.x + threadIdx.x;
    if (e < n_edges) {
        int p = atomicAdd(&cursor[dst[e]], 1);
        csr_src[p] = src[e];
    }
}

// transpose weights into [k4][f][kk] layout
__global__ void wtrans(float* __restrict__ out, const float* __restrict__ W) {
    int t = blockIdx.x * blockDim.x + threadIdx.x;
    if (t < 4096) {
        int kk = t & 3, f = (t >> 2) & 63, k4 = t >> 8;
        out[t] = W[f * 64 + k4 * 4 + kk];
    }
}

// f32 -> bf16 (RNE) elementwise
__global__ void f2bf_kern(ushort_t* __restrict__ o, const float* __restrict__ in, int n) {
    int t = blockIdx.x * blockDim.x + threadIdx.x;
    if (t < n) o[t] = f2bf_rne(in[t]);
}

// ---------------- pooling helpers ----------------

__global__ void pool_init(float* __restrict__ pooled, int n) {
    int t = blockIdx.x * blockDim.x + threadIdx.x;
    if (t < n) pooled[t] = -INFINITY;
}

__device__ __forceinline__ void atomicMaxFloat(float* addr, float value) {
    if (value >= 0.0f)
        atomicMax((int*)addr, __float_as_int(value));
    else
        atomicMin((unsigned int*)addr, (unsigned int)__float_as_int(value));
}

// ---------------- fused SAGE layer ----------------
// r16 structure (256 threads, WL in 16KB LDS -> 8 blocks/CU, WrT from global
// L1-hot, r4 8-deep readlane gather). This round: gather reads a BF16 shadow
// copy of h (halves gather bytes + cache footprint: 12.8 -> 6.4 MB); self
// term, weights, accumulation all stay f32. Epilogue writes f32 out + bf16
// shadow for the next layer.
__global__ __launch_bounds__(NT, 8) void sage_layer(
    float* __restrict__ out, ushort_t* __restrict__ out_bf,
    float* __restrict__ pooled,
    const float* __restrict__ h_in, const ushort_t* __restrict__ hb_in,
    const int* __restrict__ row_off, const int* __restrict__ csr_src,
    const int* __restrict__ batch,
    const float* __restrict__ Wl, const float* __restrict__ WrT,
    const float* __restrict__ bl,
    int n_nodes, int do_pool) {
    __shared__ float WL[4096];  // WL[k4*256 + f*4 + kk] = Wl[f][k4*4+kk]
    int tid = threadIdx.x;
    for (int t = tid; t < 4096; t += NT) {
        int kk = t & 3, f = (t >> 2) & 63, k4 = t >> 8;
        WL[t] = Wl[f * 64 + k4 * 4 + kk];
    }
    __syncthreads();

    int lane = tid & 63;
    int gwave = (blockIdx.x * NT + tid) >> 6;
    int nwaves = (gridDim.x * NT) >> 6;
    float bias = bl[lane];

    for (int q = gwave; q * 4 < n_nodes; q += nwaves) {
        int base = q * 4;
        float mean0 = 0.f, mean1 = 0.f, mean2 = 0.f, mean3 = 0.f;
        float hv0 = 0.f, hv1 = 0.f, hv2 = 0.f, hv3 = 0.f;

#define GATHER_NODE(MEAN, HV, N)                                              \
        {                                                                     \
            int i = base + (N);                                               \
            if (i < n_nodes) {                                                \
                int beg = row_off[i];                                         \
                int end_ = row_off[i + 1];                                    \
                int deg = end_ - beg;                                         \
                float a0 = 0.f, a1 = 0.f;                                     \
                for (int cb = beg; cb < end_; cb += 64) {                     \
                    int m = end_ - cb; if (m > 64) m = 64;                    \
                    int lidx = cb + (lane < m ? lane : m - 1);                \
                    int idx = csr_src[lidx];                                  \
                    for (int j = 0; j < m; j += 8) {                          \
                        int mm1 = m - 1;                                      \
                        int s0 = rli(idx, j);                                 \
                        int s1 = rli(idx, j + 1 < m ? j + 1 : mm1);           \
                        int s2 = rli(idx, j + 2 < m ? j + 2 : mm1);           \
                        int s3 = rli(idx, j + 3 < m ? j + 3 : mm1);           \
                        int s4 = rli(idx, j + 4 < m ? j + 4 : mm1);           \
                        int s5 = rli(idx, j + 5 < m ? j + 5 : mm1);           \
                        int s6 = rli(idx, j + 6 < m ? j + 6 : mm1);           \
                        int s7 = rli(idx, j + 7 < m ? j + 7 : mm1);           \
                        float v0 = bf2f(hb_in[(s0 << 6) + lane]);             \
                        float v1 = bf2f(hb_in[(s1 << 6) + lane]);             \
                        float v2 = bf2f(hb_in[(s2 << 6) + lane]);             \
                        float v3 = bf2f(hb_in[(s3 << 6) + lane]);             \
                        float v4 = bf2f(hb_in[(s4 << 6) + lane]);             \
                        float v5 = bf2f(hb_in[(s5 << 6) + lane]);             \
                        float v6 = bf2f(hb_in[(s6 << 6) + lane]);             \
                        float v7 = bf2f(hb_in[(s7 << 6) + lane]);             \
                        a0 += v0;                                             \
                        a1 += (j + 1 < m) ? v1 : 0.f;                         \
                        a0 += (j + 2 < m) ? v2 : 0.f;                         \
                        a1 += (j + 3 < m) ? v3 : 0.f;                         \
                        a0 += (j + 4 < m) ? v4 : 0.f;                         \
                        a1 += (j + 5 < m) ? v5 : 0.f;                         \
                        a0 += (j + 6 < m) ? v6 : 0.f;                         \
                        a1 += (j + 7 < m) ? v7 : 0.f;                         \
                    }                                                         \
                }                                                             \
                MEAN = (a0 + a1) * (1.0f / (float)(deg > 0 ? deg : 1));       \
                HV = h_in[(size_t)i * 64 + lane];                             \
            }                                                                 \
        }

        GATHER_NODE(mean0, hv0, 0)
        GATHER_NODE(mean1, hv1, 1)
        GATHER_NODE(mean2, hv2, 2)
        GATHER_NODE(mean3, hv3, 3)
#undef GATHER_NODE

        float o0 = bias, o1 = bias, o2 = bias, o3 = bias;
        for (int k4 = 0; k4 < 16; ++k4) {
            float4 wl = *(const float4*)&WL[k4 * 256 + lane * 4];
            float4 wr = *(const float4*)&WrT[k4 * 256 + lane * 4];
            int kb = k4 * 4;
#define DENSE_KK(WLK, WRK, KK)                                                \
            {                                                                 \
                int k = kb + (KK);                                            \
                o0 += rlf(mean0, k) * (WLK) + rlf(hv0, k) * (WRK);            \
                o1 += rlf(mean1, k) * (WLK) + rlf(hv1, k) * (WRK);            \
                o2 += rlf(mean2, k) * (WLK) + rlf(hv2, k) * (WRK);            \
                o3 += rlf(mean3, k) * (WLK) + rlf(hv3, k) * (WRK);            \
            }
            DENSE_KK(wl.x, wr.x, 0)
            DENSE_KK(wl.y, wr.y, 1)
            DENSE_KK(wl.z, wr.z, 2)
            DENSE_KK(wl.w, wr.w, 3)
#undef DENSE_KK
        }

        o0 = tanhf(o0); o1 = tanhf(o1); o2 = tanhf(o2); o3 = tanhf(o3);

#define WRITE_NODE(O, N)                                                      \
        {                                                                     \
            int i = base + (N);                                               \
            if (i < n_nodes) {                                                \
                if (do_pool) {                                                \
                    atomicMaxFloat(&pooled[(size_t)batch[i] * 64 + lane], O); \
                } else {                                                      \
                    out[(size_t)i * 64 + lane] = O;                           \
                    out_bf[(size_t)i * 64 + lane] = f2bf_rne(O);              \
                }                                                             \
            }                                                                 \
        }
        WRITE_NODE(o0, 0)
        WRITE_NODE(o1, 1)
        WRITE_NODE(o2, 2)
        WRITE_NODE(o3, 3)
#undef WRITE_NODE
    }
}

// ---------------- MLP head ----------------
__global__ void head(float* __restrict__ out, const float* __restrict__ pooled,
                     const float* __restrict__ W1, const float* __restrict__ b1,
                     const float* __restrict__ W2, const float* __restrict__ b2) {
    __shared__ float W1T[64][64];
    int tid = threadIdx.x;
    for (int t = tid; t < 4096; t += NT) {
        int f = t >> 6, k = t & 63;
        W1T[k][f] = W1[t];
    }
    __syncthreads();

    int lane = tid & 63;
    int g = blockIdx.x * (NT >> 6) + (tid >> 6);
    float v = pooled[(size_t)g * 64 + lane];
    float bias = b1[lane];
#pragma unroll
    for (int it = 0; it < 3; ++it) {
        float acc = bias;
#pragma unroll
        for (int k = 0; k < 64; ++k) {
            acc += rlf(v, k) * W1T[k][lane];
        }
        v = tanhf(acc);
    }
#pragma unroll
    for (int j = 0; j < 3; ++j) {
        float p = v * W2[j * 64 + lane];
#pragma unroll
        for (int off = 32; off >= 1; off >>= 1) p += __shfl_xor(p, off);
        if (lane == 0) out[g * 3 + j] = p + b2[j];
    }
}

// ---------------- launch ----------------

extern "C" void kernel_launch(void* const* d_in, const int* in_sizes, int n_in,
                              void* d_out, int out_size, void* d_ws, size_t ws_size,
                              hipStream_t stream) {
    const float* x   = (const float*)d_in[0];
    const float* Wl0 = (const float*)d_in[1];
    const float* Wr0 = (const float*)d_in[2];
    const float* bl0 = (const float*)d_in[3];
    const float* Wl  = (const float*)d_in[4];
    const float* Wr  = (const float*)d_in[5];
    const float* bl  = (const float*)d_in[6];
    const float* W1  = (const float*)d_in[7];
    const float* b1  = (const float*)d_in[8];
    const float* W2  = (const float*)d_in[9];
    const float* b2  = (const float*)d_in[10];
    const int* ei    = (const int*)d_in[11];
    const int* batch = (const int*)d_in[12];

    int n_nodes = in_sizes[0] / 64;
    int n_edges = in_sizes[11] / 2;
    const int* src = ei;
    const int* dst = ei + n_edges;

    int nb = (n_nodes + NT - 1) / NT;
    size_t nfeat = (size_t)n_nodes * 64;

    float* bufA   = (float*)d_ws;                         // n_nodes*64 f32
    float* bufB   = bufA + nfeat;                         // n_nodes*64 f32
    int* csr_src  = (int*)(bufB + nfeat);                 // n_edges
    int* row_off  = csr_src + n_edges;                    // n_nodes+1
    int* cursor   = row_off + (n_nodes + 1);              // n_nodes
    int* cnt      = cursor + n_nodes;                     // n_nodes
    int* bsum     = cnt + n_nodes;                        // nb
    int* boff     = bsum + nb;                            // nb
    float* pooled = (float*)(boff + nb);                  // 128*64
    float* wr0t   = pooled + 128 * 64;                    // 4096
    float* wrt    = wr0t + 4096;                          // 4096
    ushort_t* bfA = (ushort_t*)(wrt + 4096);              // n_nodes*64 bf16
    ushort_t* bfB = bfA + nfeat;                          // n_nodes*64 bf16

    int eblk = (n_edges + NT - 1) / NT;
    const int pers_blk = 2048;  // 8 blocks/CU x 256 CUs

    // CSR build (parallel scan)
    zero_i32<<<nb, NT, 0, stream>>>(cnt, n_nodes);
    hist_dst<<<eblk, NT, 0, stream>>>(cnt, dst, n_edges);
    scan_blocks<<<nb, NT, 0, stream>>>(cnt, bsum, n_nodes);
    scan_bsum<<<1, 1024, 0, stream>>>(bsum, boff, nb, row_off, n_nodes);
    scan_final<<<nb, NT, 0, stream>>>(cnt, boff, row_off, cursor, n_nodes);
    edge_scatter<<<eblk, NT, 0, stream>>>(csr_src, cursor, src, dst, n_edges);

    // transposed WR copies, bf16 copy of x, pool init
    wtrans<<<16, NT, 0, stream>>>(wr0t, Wr0);
    wtrans<<<16, NT, 0, stream>>>(wrt, Wr);
    f2bf_kern<<<(int)((nfeat + NT - 1) / NT), NT, 0, stream>>>(bfA, x, (int)nfeat);
    pool_init<<<(128 * 64 + NT - 1) / NT, NT, 0, stream>>>(pooled, 128 * 64);

    // L0: gather bfA (x), hv x -> bufA + bfB
    sage_layer<<<pers_blk, NT, 0, stream>>>(bufA, bfB, pooled, x, bfA,
                                            row_off, csr_src, batch,
                                            Wl0, wr0t, bl0, n_nodes, 0);
    // L1: gather bfB, hv bufA -> bufB + bfA
    sage_layer<<<pers_blk, NT, 0, stream>>>(bufB, bfA, pooled, bufA, bfB,
                                            row_off, csr_src, batch,
                                            Wl, wrt, bl, n_nodes, 0);
    // L2: gather bfA, hv bufB -> bufA + bfB
    sage_layer<<<pers_blk, NT, 0, stream>>>(bufA, bfB, pooled, bufB, bfA,
                                            row_off, csr_src, batch,
                                            Wl, wrt, bl, n_nodes, 0);
    // L3: gather bfB, hv bufA -> pooled
    sage_layer<<<pers_blk, NT, 0, stream>>>(bufB, bfA, pooled, bufA, bfB,
                                            row_off, csr_src, batch,
                                            Wl, wrt, bl, n_nodes, 1);

    head<<<32, NT, 0, stream>>>((float*)d_out, pooled, W1, b1, W2, b2);
}

// Round 18
// 396.646 us; speedup vs baseline: 1.1569x; 1.1569x over previous
//
#include <hip/hip_runtime.h>
#include <math.h>

#define NT 256

typedef unsigned short ushort_t;
typedef unsigned int uint_t;
typedef __attribute__((ext_vector_type(8))) short bf16x8;
typedef __attribute__((ext_vector_type(4))) float f32x4;

__device__ __forceinline__ int rli(int v, int l) {
    return __builtin_amdgcn_readlane(v, l);
}
__device__ __forceinline__ int imax(int a, int b) { return a > b ? a : b; }

__device__ __forceinline__ ushort_t f2bf_rne(float f) {
    uint_t u = __float_as_uint(f);
    uint_t r = u + 0x7FFF + ((u >> 16) & 1);
    return (ushort_t)(r >> 16);
}
__device__ __forceinline__ float bf2f(ushort_t b) {
    return __uint_as_float(((uint_t)b) << 16);
}
__device__ __forceinline__ float rlf(float v, int l) {
    return __int_as_float(__builtin_amdgcn_readlane(__float_as_int(v), l));
}

// ---------------- CSR build ----------------

__global__ void zero_i32(int* __restrict__ p, int n) {
    int t = blockIdx.x * blockDim.x + threadIdx.x;
    if (t < n) p[t] = 0;
}

__global__ void hist_dst(int* __restrict__ cnt, const int* __restrict__ dst, int n_edges) {
    int e = blockIdx.x * blockDim.x + threadIdx.x;
    if (e < n_edges) atomicAdd(&cnt[dst[e]], 1);
}

__global__ void scan_blocks(const int* __restrict__ cnt, int* __restrict__ bsum, int n) {
    __shared__ int s[NT];
    int i = blockIdx.x * NT + threadIdx.x;
    s[threadIdx.x] = (i < n) ? cnt[i] : 0;
    __syncthreads();
    for (int off = NT / 2; off > 0; off >>= 1) {
        if (threadIdx.x < off) s[threadIdx.x] += s[threadIdx.x + off];
        __syncthreads();
    }
    if (threadIdx.x == 0) bsum[blockIdx.x] = s[0];
}

__global__ void scan_bsum(const int* __restrict__ bsum, int* __restrict__ boff,
                          int nb, int* __restrict__ row_off, int n) {
    __shared__ int s[1024];
    int tid = threadIdx.x;
    int v = (tid < nb) ? bsum[tid] : 0;
    s[tid] = v;
    __syncthreads();
    for (int off = 1; off < 1024; off <<= 1) {
        int t = (tid >= off) ? s[tid - off] : 0;
        __syncthreads();
        s[tid] += t;
        __syncthreads();
    }
    if (tid < nb) boff[tid] = s[tid] - v;
    if (tid == nb - 1) row_off[n] = s[tid];
}

__global__ void scan_final(const int* __restrict__ cnt, const int* __restrict__ boff,
                           int* __restrict__ row_off, int* __restrict__ cursor, int n) {
    __shared__ int s[NT];
    int i = blockIdx.x * NT + threadIdx.x;
    int v = (i < n) ? cnt[i] : 0;
    s[threadIdx.x] = v;
    __syncthreads();
    for (int off = 1; off < NT; off <<= 1) {
        int t = (threadIdx.x >= off) ? s[threadIdx.x - off] : 0;
        __syncthreads();
        s[threadIdx.x] += t;
        __syncthreads();
    }
    if (i < n) {
        int ex = boff[blockIdx.x] + s[threadIdx.x] - v;
        row_off[i] = ex;
        cursor[i] = ex;
    }
}

__global__ void edge_scatter(int* __restrict__ csr_src, int* __restrict__ cursor,
                             const int* __restrict__ src, const int* __restrict__ dst,
                             int n_edges) {
    int e = blockIdx.x * blockDim.x + threadIdx.x;
    if (e < n_edges) {
        int p = atomicAdd(&cursor[dst[e]], 1);
        csr_src[p] = src[e];
    }
}

// ---------------- prep kernels ----------------

// f32 -> bf16 elementwise (RNE)
__global__ void f2bf_kern(ushort_t* __restrict__ o, const float* __restrict__ in, int n) {
    int t = blockIdx.x * blockDim.x + threadIdx.x;
    if (t < n) o[t] = f2bf_rne(in[t]);
}

// Pack combined weights into MFMA B-fragment order, bf16.
// B[k][f] = Wl[f][k] (k<64) | Wr[f][k-64]. Fragment (ks,nt): lane l, elem i
// covers k = ks*32 + (l>>4)*8 + i, f = nt*16 + (l&15).
// packed[(((ks*4)+nt)*64 + lane)*8 + i]
__global__ void pack_w(ushort_t* __restrict__ packed, const float* __restrict__ Wl,
                       const float* __restrict__ Wr) {
    int t = blockIdx.x * blockDim.x + threadIdx.x;
    if (t < 8192) {
        int i = t & 7;
        int lane = (t >> 3) & 63;
        int nt = (t >> 9) & 3;
        int ks = t >> 11;
        int k = ks * 32 + ((lane >> 4) << 3) + i;
        int f = nt * 16 + (lane & 15);
        float w = (k < 64) ? Wl[f * 64 + k] : Wr[f * 64 + (k - 64)];
        packed[t] = f2bf_rne(w);
    }
}

// ---------------- pooling helpers ----------------

__global__ void pool_init(float* __restrict__ pooled, int n) {
    int t = blockIdx.x * blockDim.x + threadIdx.x;
    if (t < n) pooled[t] = -INFINITY;
}

__device__ __forceinline__ void atomicMaxFloat(float* addr, float value) {
    if (value >= 0.0f)
        atomicMax((int*)addr, __float_as_int(value));
    else
        atomicMin((unsigned int*)addr, (unsigned int)__float_as_int(value));
}

// ---------------- fused SAGE layer: bf16 gather + MFMA dense ----------------
// Block = 256 thr = 4 waves = 32 nodes. Phase 1: wave v gathers nodes
// v*8..v*8+7 (r17-proven 8-deep readlane gather on bf16 shadow), writes
// A_tile[32][136] bf16: cols 0-63 = mean, 64-127 = h. Pad 136 -> 2-way-free
// ds_read_b128 fragments. Phase 2: wave v computes (rowtile=v>>1,
// nt=(v&1)*2+p) output tiles: 4 K-steps of mfma_f32_16x16x32_bf16 (K=128
// fuses mean@Wl^T + h@Wr^T). Epilogue: +bias, tanh, bf16 store / pool-max.
__global__ __launch_bounds__(NT, 8) void sage_layer(
    ushort_t* __restrict__ out_bf, float* __restrict__ pooled,
    const ushort_t* __restrict__ hb_in,
    const int* __restrict__ row_off, const int* __restrict__ csr_src,
    const int* __restrict__ batch,
    const ushort_t* __restrict__ pw,  // packed B fragments (16KB)
    const float* __restrict__ bl,
    int n_nodes, int do_pool) {
    __shared__ ushort_t A[32 * 136];
    int tid = threadIdx.x;
    int lane = tid & 63;
    int v = tid >> 6;  // wave 0..3
    int g0 = blockIdx.x * 32 + v * 8;

    // ---- phase 1: gather 8 nodes into A_tile ----
    int roidx = g0 + (lane < 9 ? lane : 8);
    if (roidx > n_nodes) roidx = n_nodes;
    int ro = row_off[roidx];

#pragma unroll
    for (int n = 0; n < 8; ++n) {
        int g = g0 + n;
        int row = v * 8 + n;
        if (g < n_nodes) {
            int b = rli(ro, n);
            int e_ = rli(ro, n + 1);
            int d = e_ - b;
            float mean = 0.f;
            if (d <= 64) {
                int idx = csr_src[b + (lane < d ? lane : imax(d - 1, 0))];
                float a0 = 0.f, a1 = 0.f;
                for (int j = 0; j < d; j += 8) {
                    int mm1 = d - 1;
                    int s0 = rli(idx, j);
                    int s1 = rli(idx, j + 1 < d ? j + 1 : mm1);
                    int s2 = rli(idx, j + 2 < d ? j + 2 : mm1);
                    int s3 = rli(idx, j + 3 < d ? j + 3 : mm1);
                    int s4 = rli(idx, j + 4 < d ? j + 4 : mm1);
                    int s5 = rli(idx, j + 5 < d ? j + 5 : mm1);
                    int s6 = rli(idx, j + 6 < d ? j + 6 : mm1);
                    int s7 = rli(idx, j + 7 < d ? j + 7 : mm1);
                    float v0 = bf2f(hb_in[(s0 << 6) + lane]);
                    float v1 = bf2f(hb_in[(s1 << 6) + lane]);
                    float v2 = bf2f(hb_in[(s2 << 6) + lane]);
                    float v3 = bf2f(hb_in[(s3 << 6) + lane]);
                    float v4 = bf2f(hb_in[(s4 << 6) + lane]);
                    float v5 = bf2f(hb_in[(s5 << 6) + lane]);
                    float v6 = bf2f(hb_in[(s6 << 6) + lane]);
                    float v7 = bf2f(hb_in[(s7 << 6) + lane]);
                    a0 += v0;
                    a1 += (j + 1 < d) ? v1 : 0.f;
                    a0 += (j + 2 < d) ? v2 : 0.f;
                    a1 += (j + 3 < d) ? v3 : 0.f;
                    a0 += (j + 4 < d) ? v4 : 0.f;
                    a1 += (j + 5 < d) ? v5 : 0.f;
                    a0 += (j + 6 < d) ? v6 : 0.f;
                    a1 += (j + 7 < d) ? v7 : 0.f;
                }
                mean = (a0 + a1) * (1.0f / (float)imax(d, 1));
            } else {
                // slow path: deg > 64, chunked
                float aa = 0.f;
                for (int cb = b; cb < e_; cb += 64) {
                    int m = e_ - cb; if (m > 64) m = 64;
                    int lidx = cb + (lane < m ? lane : m - 1);
                    int idx = csr_src[lidx];
                    for (int j = 0; j < m; ++j)
                        aa += bf2f(hb_in[(rli(idx, j) << 6) + lane]);
                }
                mean = aa * (1.0f / (float)imax(d, 1));
            }
            A[row * 136 + lane] = f2bf_rne(mean);
            A[row * 136 + 64 + lane] = hb_in[(size_t)g * 64 + lane];
        } else {
            A[row * 136 + lane] = 0;
            A[row * 136 + 64 + lane] = 0;
        }
    }
    __syncthreads();

    // ---- phase 2: MFMA dense ----
    int rowtile = v >> 1;
    int a_row = rowtile * 16 + (lane & 15);
    int kbase = (lane >> 4) << 3;
#pragma unroll
    for (int p = 0; p < 2; ++p) {
        int nt = (v & 1) * 2 + p;
        f32x4 acc = {0.f, 0.f, 0.f, 0.f};
#pragma unroll
        for (int ks = 0; ks < 4; ++ks) {
            bf16x8 af = *reinterpret_cast<const bf16x8*>(&A[a_row * 136 + ks * 32 + kbase]);
            bf16x8 bf = *reinterpret_cast<const bf16x8*>(&pw[(((ks << 2) + nt) * 64 + lane) << 3]);
            acc = __builtin_amdgcn_mfma_f32_16x16x32_bf16(af, bf, acc, 0, 0, 0);
        }
        int c = nt * 16 + (lane & 15);
        float bias = bl[c];
        int rbase = blockIdx.x * 32 + rowtile * 16 + ((lane >> 4) << 2);
#pragma unroll
        for (int j = 0; j < 4; ++j) {
            int g = rbase + j;
            if (g < n_nodes) {
                float o = tanhf(acc[j] + bias);
                if (do_pool) {
                    atomicMaxFloat(&pooled[(size_t)batch[g] * 64 + c], o);
                } else {
                    out_bf[(size_t)g * 64 + c] = f2bf_rne(o);
                }
            }
        }
    }
}

// ---------------- MLP head ----------------
__global__ void head(float* __restrict__ out, const float* __restrict__ pooled,
                     const float* __restrict__ W1, const float* __restrict__ b1,
                     const float* __restrict__ W2, const float* __restrict__ b2) {
    __shared__ float W1T[64][64];
    int tid = threadIdx.x;
    for (int t = tid; t < 4096; t += NT) {
        int f = t >> 6, k = t & 63;
        W1T[k][f] = W1[t];
    }
    __syncthreads();

    int lane = tid & 63;
    int g = blockIdx.x * (NT >> 6) + (tid >> 6);
    float v = pooled[(size_t)g * 64 + lane];
    float bias = b1[lane];
#pragma unroll
    for (int it = 0; it < 3; ++it) {
        float acc = bias;
#pragma unroll
        for (int k = 0; k < 64; ++k) {
            acc += rlf(v, k) * W1T[k][lane];
        }
        v = tanhf(acc);
    }
#pragma unroll
    for (int j = 0; j < 3; ++j) {
        float p = v * W2[j * 64 + lane];
#pragma unroll
        for (int off = 32; off >= 1; off >>= 1) p += __shfl_xor(p, off);
        if (lane == 0) out[g * 3 + j] = p + b2[j];
    }
}

// ---------------- launch ----------------

extern "C" void kernel_launch(void* const* d_in, const int* in_sizes, int n_in,
                              void* d_out, int out_size, void* d_ws, size_t ws_size,
                              hipStream_t stream) {
    const float* x   = (const float*)d_in[0];
    const float* Wl0 = (const float*)d_in[1];
    const float* Wr0 = (const float*)d_in[2];
    const float* bl0 = (const float*)d_in[3];
    const float* Wl  = (const float*)d_in[4];
    const float* Wr  = (const float*)d_in[5];
    const float* bl  = (const float*)d_in[6];
    const float* W1  = (const float*)d_in[7];
    const float* b1  = (const float*)d_in[8];
    const float* W2  = (const float*)d_in[9];
    const float* b2  = (const float*)d_in[10];
    const int* ei    = (const int*)d_in[11];
    const int* batch = (const int*)d_in[12];

    int n_nodes = in_sizes[0] / 64;
    int n_edges = in_sizes[11] / 2;
    const int* src = ei;
    const int* dst = ei + n_edges;

    int nb = (n_nodes + NT - 1) / NT;
    size_t nfeat = (size_t)n_nodes * 64;

    int* csr_src  = (int*)d_ws;                           // n_edges
    int* row_off  = csr_src + n_edges;                    // n_nodes+1
    int* cursor   = row_off + (n_nodes + 1);              // n_nodes
    int* cnt      = cursor + n_nodes;                     // n_nodes
    int* bsum     = cnt + n_nodes;                        // nb
    int* boff     = bsum + nb;                            // nb
    float* pooled = (float*)(boff + nb);                  // 128*64
    ushort_t* pw0 = (ushort_t*)(pooled + 128 * 64);       // 8192
    ushort_t* pw  = pw0 + 8192;                           // 8192
    ushort_t* bfX = pw + 8192;                            // nfeat
    ushort_t* bfA = bfX + nfeat;                          // nfeat
    ushort_t* bfB = bfA + nfeat;                          // nfeat

    int eblk = (n_edges + NT - 1) / NT;
    int sage_blk = (n_nodes + 31) / 32;  // 1563

    // CSR build (parallel scan)
    zero_i32<<<nb, NT, 0, stream>>>(cnt, n_nodes);
    hist_dst<<<eblk, NT, 0, stream>>>(cnt, dst, n_edges);
    scan_blocks<<<nb, NT, 0, stream>>>(cnt, bsum, n_nodes);
    scan_bsum<<<1, 1024, 0, stream>>>(bsum, boff, nb, row_off, n_nodes);
    scan_final<<<nb, NT, 0, stream>>>(cnt, boff, row_off, cursor, n_nodes);
    edge_scatter<<<eblk, NT, 0, stream>>>(csr_src, cursor, src, dst, n_edges);

    // prep: bf16 x, packed weights, pool init
    f2bf_kern<<<(int)((nfeat + NT - 1) / NT), NT, 0, stream>>>(bfX, x, (int)nfeat);
    pack_w<<<32, NT, 0, stream>>>(pw0, Wl0, Wr0);
    pack_w<<<32, NT, 0, stream>>>(pw, Wl, Wr);
    pool_init<<<(128 * 64 + NT - 1) / NT, NT, 0, stream>>>(pooled, 128 * 64);

    // layers (all-bf16 inter-layer state)
    sage_layer<<<sage_blk, NT, 0, stream>>>(bfA, pooled, bfX, row_off, csr_src,
                                            batch, pw0, bl0, n_nodes, 0);
    sage_layer<<<sage_blk, NT, 0, stream>>>(bfB, pooled, bfA, row_off, csr_src,
                                            batch, pw, bl, n_nodes, 0);
    sage_layer<<<sage_blk, NT, 0, stream>>>(bfA, pooled, bfB, row_off, csr_src,
                                            batch, pw, bl, n_nodes, 0);
    sage_layer<<<sage_blk, NT, 0, stream>>>(bfB, pooled, bfA, row_off, csr_src,
                                            batch, pw, bl, n_nodes, 1);

    head<<<32, NT, 0, stream>>>((float*)d_out, pooled, W1, b1, W2, b2);
}

// Round 20
// 390.007 us; speedup vs baseline: 1.1766x; 1.0170x over previous
//
#include <hip/hip_runtime.h>
#include <math.h>

#define NT 256
#define NTS 128   // sage_layer: 2 waves, 16-node tile

typedef unsigned short ushort_t;
typedef unsigned int uint_t;
typedef __attribute__((ext_vector_type(8))) short bf16x8;
typedef __attribute__((ext_vector_type(4))) float f32x4;

__device__ __forceinline__ int rli(int v, int l) {
    return __builtin_amdgcn_readlane(v, l);
}
__device__ __forceinline__ int imax(int a, int b) { return a > b ? a : b; }

__device__ __forceinline__ ushort_t f2bf_rne(float f) {
    uint_t u = __float_as_uint(f);
    uint_t r = u + 0x7FFF + ((u >> 16) & 1);
    return (ushort_t)(r >> 16);
}
__device__ __forceinline__ float bf2f(ushort_t b) {
    return __uint_as_float(((uint_t)b) << 16);
}
__device__ __forceinline__ float rlf(float v, int l) {
    return __int_as_float(__builtin_amdgcn_readlane(__float_as_int(v), l));
}

// ---------------- CSR build ----------------

__global__ void zero_i32(int* __restrict__ p, int n) {
    int t = blockIdx.x * blockDim.x + threadIdx.x;
    if (t < n) p[t] = 0;
}

__global__ void hist_dst(int* __restrict__ cnt, const int* __restrict__ dst, int n_edges) {
    int e = blockIdx.x * blockDim.x + threadIdx.x;
    if (e < n_edges) atomicAdd(&cnt[dst[e]], 1);
}

__global__ void scan_blocks(const int* __restrict__ cnt, int* __restrict__ bsum, int n) {
    __shared__ int s[NT];
    int i = blockIdx.x * NT + threadIdx.x;
    s[threadIdx.x] = (i < n) ? cnt[i] : 0;
    __syncthreads();
    for (int off = NT / 2; off > 0; off >>= 1) {
        if (threadIdx.x < off) s[threadIdx.x] += s[threadIdx.x + off];
        __syncthreads();
    }
    if (threadIdx.x == 0) bsum[blockIdx.x] = s[0];
}

__global__ void scan_bsum(const int* __restrict__ bsum, int* __restrict__ boff,
                          int nb, int* __restrict__ row_off, int n) {
    __shared__ int s[1024];
    int tid = threadIdx.x;
    int v = (tid < nb) ? bsum[tid] : 0;
    s[tid] = v;
    __syncthreads();
    for (int off = 1; off < 1024; off <<= 1) {
        int t = (tid >= off) ? s[tid - off] : 0;
        __syncthreads();
        s[tid] += t;
        __syncthreads();
    }
    if (tid < nb) boff[tid] = s[tid] - v;
    if (tid == nb - 1) row_off[n] = s[tid];
}

__global__ void scan_final(const int* __restrict__ cnt, const int* __restrict__ boff,
                           int* __restrict__ row_off, int* __restrict__ cursor, int n) {
    __shared__ int s[NT];
    int i = blockIdx.x * NT + threadIdx.x;
    int v = (i < n) ? cnt[i] : 0;
    s[threadIdx.x] = v;
    __syncthreads();
    for (int off = 1; off < NT; off <<= 1) {
        int t = (threadIdx.x >= off) ? s[threadIdx.x - off] : 0;
        __syncthreads();
        s[threadIdx.x] += t;
        __syncthreads();
    }
    if (i < n) {
        int ex = boff[blockIdx.x] + s[threadIdx.x] - v;
        row_off[i] = ex;
        cursor[i] = ex;
    }
}

__global__ void edge_scatter(int* __restrict__ csr_src, int* __restrict__ cursor,
                             const int* __restrict__ src, const int* __restrict__ dst,
                             int n_edges) {
    int e = blockIdx.x * blockDim.x + threadIdx.x;
    if (e < n_edges) {
        int p = atomicAdd(&cursor[dst[e]], 1);
        csr_src[p] = src[e];
    }
}

// ---------------- prep kernels ----------------

__global__ void f2bf_kern(ushort_t* __restrict__ o, const float* __restrict__ in, int n) {
    int t = blockIdx.x * blockDim.x + threadIdx.x;
    if (t < n) o[t] = f2bf_rne(in[t]);
}

// Pack combined weights into MFMA B-fragment order, bf16 (see r18).
__global__ void pack_w(ushort_t* __restrict__ packed, const float* __restrict__ Wl,
                       const float* __restrict__ Wr) {
    int t = blockIdx.x * blockDim.x + threadIdx.x;
    if (t < 8192) {
        int i = t & 7;
        int lane = (t >> 3) & 63;
        int nt = (t >> 9) & 3;
        int ks = t >> 11;
        int k = ks * 32 + ((lane >> 4) << 3) + i;
        int f = nt * 16 + (lane & 15);
        float w = (k < 64) ? Wl[f * 64 + k] : Wr[f * 64 + (k - 64)];
        packed[t] = f2bf_rne(w);
    }
}

// ---------------- pooling helpers ----------------

__global__ void pool_init(float* __restrict__ pooled, int n) {
    int t = blockIdx.x * blockDim.x + threadIdx.x;
    if (t < n) pooled[t] = -INFINITY;
}

__device__ __forceinline__ void atomicMaxFloat(float* addr, float value) {
    if (value >= 0.0f)
        atomicMax((int*)addr, __float_as_int(value));
    else
        atomicMin((unsigned int*)addr, (unsigned int)__float_as_int(value));
}

// ---------------- fused SAGE layer: bf16 pair-gather + MFMA dense ----------------
// Block = 128 thr = 2 waves = 16 nodes (grid 3125 fully resident -> ~76%
// occupancy ceiling). Wave v gathers nodes v*8..v*8+7 in PAIRS (16 loads in
// flight) on the bf16 shadow; A_tile[16][136]: cols 0-63 mean, 64-127 h.
// Dense: wave v computes nt=2v,2v+1 via 4 K-steps of mfma_f32_16x16x32_bf16.
__global__ __launch_bounds__(NTS, 8) void sage_layer(
    ushort_t* __restrict__ out_bf, float* __restrict__ pooled,
    const ushort_t* __restrict__ hb_in,
    const int* __restrict__ row_off, const int* __restrict__ csr_src,
    const int* __restrict__ batch,
    const ushort_t* __restrict__ pw,
    const float* __restrict__ bl,
    int n_nodes, int do_pool) {
    __shared__ ushort_t A[16 * 136];
    int tid = threadIdx.x;
    int lane = tid & 63;
    int v = tid >> 6;  // wave 0..1
    int g0 = blockIdx.x * 16 + v * 8;

    int roidx = g0 + (lane < 9 ? lane : 8);
    if (roidx > n_nodes) roidx = n_nodes;
    int ro = row_off[roidx];

#pragma unroll
    for (int p = 0; p < 4; ++p) {
        int nA = 2 * p, nB = 2 * p + 1;
        int gA = g0 + nA, gB = g0 + nB;
        int rowA = v * 8 + nA, rowB = v * 8 + nB;
        int bA = rli(ro, nA), eA = rli(ro, nA + 1);
        int bB = rli(ro, nB), eB = rli(ro, nB + 1);
        int dA = eA - bA, dB = eB - bB;
        bool okA = gA < n_nodes, okB = gB < n_nodes;
        float meanA = 0.f, meanB = 0.f;

        if (okA && okB && dA <= 64 && dB <= 64) {
            // ---- pair-interleaved fast path: 16 loads in flight ----
            int idxA = csr_src[bA + (lane < dA ? lane : imax(dA - 1, 0))];
            int idxB = csr_src[bB + (lane < dB ? lane : imax(dB - 1, 0))];
            int gmax = imax(dA, dB);
            float aA0 = 0.f, aA1 = 0.f, aB0 = 0.f, aB1 = 0.f;
            for (int j = 0; j < gmax; j += 8) {
                float vA0, vA1, vA2, vA3, vA4, vA5, vA6, vA7;
                float vB0, vB1, vB2, vB3, vB4, vB5, vB6, vB7;
                bool doA = j < dA, doB = j < dB;
                if (doA) {
                    int mm = dA - 1;
                    vA0 = bf2f(hb_in[(rli(idxA, j) << 6) + lane]);
                    vA1 = bf2f(hb_in[(rli(idxA, j + 1 < dA ? j + 1 : mm) << 6) + lane]);
                    vA2 = bf2f(hb_in[(rli(idxA, j + 2 < dA ? j + 2 : mm) << 6) + lane]);
                    vA3 = bf2f(hb_in[(rli(idxA, j + 3 < dA ? j + 3 : mm) << 6) + lane]);
                    vA4 = bf2f(hb_in[(rli(idxA, j + 4 < dA ? j + 4 : mm) << 6) + lane]);
                    vA5 = bf2f(hb_in[(rli(idxA, j + 5 < dA ? j + 5 : mm) << 6) + lane]);
                    vA6 = bf2f(hb_in[(rli(idxA, j + 6 < dA ? j + 6 : mm) << 6) + lane]);
                    vA7 = bf2f(hb_in[(rli(idxA, j + 7 < dA ? j + 7 : mm) << 6) + lane]);
                }
                if (doB) {
                    int mm = dB - 1;
                    vB0 = bf2f(hb_in[(rli(idxB, j) << 6) + lane]);
                    vB1 = bf2f(hb_in[(rli(idxB, j + 1 < dB ? j + 1 : mm) << 6) + lane]);
                    vB2 = bf2f(hb_in[(rli(idxB, j + 2 < dB ? j + 2 : mm) << 6) + lane]);
                    vB3 = bf2f(hb_in[(rli(idxB, j + 3 < dB ? j + 3 : mm) << 6) + lane]);
                    vB4 = bf2f(hb_in[(rli(idxB, j + 4 < dB ? j + 4 : mm) << 6) + lane]);
                    vB5 = bf2f(hb_in[(rli(idxB, j + 5 < dB ? j + 5 : mm) << 6) + lane]);
                    vB6 = bf2f(hb_in[(rli(idxB, j + 6 < dB ? j + 6 : mm) << 6) + lane]);
                    vB7 = bf2f(hb_in[(rli(idxB, j + 7 < dB ? j + 7 : mm) << 6) + lane]);
                }
                if (doA) {
                    aA0 += vA0;
                    aA1 += (j + 1 < dA) ? vA1 : 0.f;
                    aA0 += (j + 2 < dA) ? vA2 : 0.f;
                    aA1 += (j + 3 < dA) ? vA3 : 0.f;
                    aA0 += (j + 4 < dA) ? vA4 : 0.f;
                    aA1 += (j + 5 < dA) ? vA5 : 0.f;
                    aA0 += (j + 6 < dA) ? vA6 : 0.f;
                    aA1 += (j + 7 < dA) ? vA7 : 0.f;
                }
                if (doB) {
                    aB0 += vB0;
                    aB1 += (j + 1 < dB) ? vB1 : 0.f;
                    aB0 += (j + 2 < dB) ? vB2 : 0.f;
                    aB1 += (j + 3 < dB) ? vB3 : 0.f;
                    aB0 += (j + 4 < dB) ? vB4 : 0.f;
                    aB1 += (j + 5 < dB) ? vB5 : 0.f;
                    aB0 += (j + 6 < dB) ? vB6 : 0.f;
                    aB1 += (j + 7 < dB) ? vB7 : 0.f;
                }
            }
            meanA = (aA0 + aA1) * (1.0f / (float)imax(dA, 1));
            meanB = (aB0 + aB1) * (1.0f / (float)imax(dB, 1));
        } else {
            // ---- slow path: per-node chunked (tail or deg>64) ----
#define SLOW_NODE(MEAN, OK, B, E, D)                                          \
            if (OK) {                                                         \
                float aa = 0.f;                                               \
                for (int cb = (B); cb < (E); cb += 64) {                      \
                    int m = (E) - cb; if (m > 64) m = 64;                     \
                    int lidx = cb + (lane < m ? lane : m - 1);                \
                    int idx = csr_src[lidx];                                  \
                    for (int j = 0; j < m; ++j)                               \
                        aa += bf2f(hb_in[(rli(idx, j) << 6) + lane]);         \
                }                                                             \
                MEAN = aa * (1.0f / (float)imax((D), 1));                     \
            }
            SLOW_NODE(meanA, okA, bA, eA, dA)
            SLOW_NODE(meanB, okB, bB, eB, dB)
#undef SLOW_NODE
        }

        if (okA) {
            A[rowA * 136 + lane] = f2bf_rne(meanA);
            A[rowA * 136 + 64 + lane] = hb_in[((size_t)gA << 6) + lane];
        } else {
            A[rowA * 136 + lane] = 0;
            A[rowA * 136 + 64 + lane] = 0;
        }
        if (okB) {
            A[rowB * 136 + lane] = f2bf_rne(meanB);
            A[rowB * 136 + 64 + lane] = hb_in[((size_t)gB << 6) + lane];
        } else {
            A[rowB * 136 + lane] = 0;
            A[rowB * 136 + 64 + lane] = 0;
        }
    }
    __syncthreads();

    // ---- phase 2: MFMA dense (single 16-row tile, wave v does nt=2v,2v+1) ----
    int a_row = lane & 15;
    int kbase = (lane >> 4) << 3;
#pragma unroll
    for (int p = 0; p < 2; ++p) {
        int nt = v * 2 + p;
        f32x4 acc = {0.f, 0.f, 0.f, 0.f};
#pragma unroll
        for (int ks = 0; ks < 4; ++ks) {
            bf16x8 af = *reinterpret_cast<const bf16x8*>(&A[a_row * 136 + ks * 32 + kbase]);
            bf16x8 bf = *reinterpret_cast<const bf16x8*>(&pw[(((ks << 2) + nt) * 64 + lane) << 3]);
            acc = __builtin_amdgcn_mfma_f32_16x16x32_bf16(af, bf, acc, 0, 0, 0);
        }
        int c = nt * 16 + (lane & 15);
        float bias = bl[c];
        int rbase = blockIdx.x * 16 + ((lane >> 4) << 2);
#pragma unroll
        for (int j = 0; j < 4; ++j) {
            int g = rbase + j;
            if (g < n_nodes) {
                float o = tanhf(acc[j] + bias);
                if (do_pool) {
                    atomicMaxFloat(&pooled[(size_t)batch[g] * 64 + c], o);
                } else {
                    out_bf[(size_t)g * 64 + c] = f2bf_rne(o);
                }
            }
        }
    }
}

// ---------------- MLP head ----------------
__global__ void head(float* __restrict__ out, const float* __restrict__ pooled,
                     const float* __restrict__ W1, const float* __restrict__ b1,
                     const float* __restrict__ W2, const float* __restrict__ b2) {
    __shared__ float W1T[64][64];
    int tid = threadIdx.x;
    for (int t = tid; t < 4096; t += NT) {
        int f = t >> 6, k = t & 63;
        W1T[k][f] = W1[t];
    }
    __syncthreads();

    int lane = tid & 63;
    int g = blockIdx.x * (NT >> 6) + (tid >> 6);
    float v = pooled[(size_t)g * 64 + lane];
    float bias = b1[lane];
#pragma unroll
    for (int it = 0; it < 3; ++it) {
        float acc = bias;
#pragma unroll
        for (int k = 0; k < 64; ++k) {
            acc += rlf(v, k) * W1T[k][lane];
        }
        v = tanhf(acc);
    }
#pragma unroll
    for (int j = 0; j < 3; ++j) {
        float p = v * W2[j * 64 + lane];
#pragma unroll
        for (int off = 32; off >= 1; off >>= 1) p += __shfl_xor(p, off);
        if (lane == 0) out[g * 3 + j] = p + b2[j];
    }
}

// ---------------- launch ----------------

extern "C" void kernel_launch(void* const* d_in, const int* in_sizes, int n_in,
                              void* d_out, int out_size, void* d_ws, size_t ws_size,
                              hipStream_t stream) {
    const float* x   = (const float*)d_in[0];
    const float* Wl0 = (const float*)d_in[1];
    const float* Wr0 = (const float*)d_in[2];
    const float* bl0 = (const float*)d_in[3];
    const float* Wl  = (const float*)d_in[4];
    const float* Wr  = (const float*)d_in[5];
    const float* bl  = (const float*)d_in[6];
    const float* W1  = (const float*)d_in[7];
    const float* b1  = (const float*)d_in[8];
    const float* W2  = (const float*)d_in[9];
    const float* b2  = (const float*)d_in[10];
    const int* ei    = (const int*)d_in[11];
    const int* batch = (const int*)d_in[12];

    int n_nodes = in_sizes[0] / 64;
    int n_edges = in_sizes[11] / 2;
    const int* src = ei;
    const int* dst = ei + n_edges;

    int nb = (n_nodes + NT - 1) / NT;
    size_t nfeat = (size_t)n_nodes * 64;

    int* csr_src  = (int*)d_ws;                           // n_edges
    int* row_off  = csr_src + n_edges;                    // n_nodes+1
    int* cursor   = row_off + (n_nodes + 1);              // n_nodes
    int* cnt      = cursor + n_nodes;                     // n_nodes
    int* bsum     = cnt + n_nodes;                        // nb
    int* boff     = bsum + nb;                            // nb
    float* pooled = (float*)(boff + nb);                  // 128*64
    ushort_t* pw0 = (ushort_t*)(pooled + 128 * 64);       // 8192
    ushort_t* pw  = pw0 + 8192;                           // 8192
    ushort_t* bfX = pw + 8192;                            // nfeat
    ushort_t* bfA = bfX + nfeat;                          // nfeat
    ushort_t* bfB = bfA + nfeat;                          // nfeat

    int eblk = (n_edges + NT - 1) / NT;
    int sage_blk = (n_nodes + 15) / 16;  // 3125, fully resident

    // CSR build (parallel scan)
    zero_i32<<<nb, NT, 0, stream>>>(cnt, n_nodes);
    hist_dst<<<eblk, NT, 0, stream>>>(cnt, dst, n_edges);
    scan_blocks<<<nb, NT, 0, stream>>>(cnt, bsum, n_nodes);
    scan_bsum<<<1, 1024, 0, stream>>>(bsum, boff, nb, row_off, n_nodes);
    scan_final<<<nb, NT, 0, stream>>>(cnt, boff, row_off, cursor, n_nodes);
    edge_scatter<<<eblk, NT, 0, stream>>>(csr_src, cursor, src, dst, n_edges);

    // prep: bf16 x, packed weights, pool init
    f2bf_kern<<<(int)((nfeat + NT - 1) / NT), NT, 0, stream>>>(bfX, x, (int)nfeat);
    pack_w<<<32, NT, 0, stream>>>(pw0, Wl0, Wr0);
    pack_w<<<32, NT, 0, stream>>>(pw, Wl, Wr);
    pool_init<<<(128 * 64 + NT - 1) / NT, NT, 0, stream>>>(pooled, 128 * 64);

    // layers (all-bf16 inter-layer state)
    sage_layer<<<sage_blk, NTS, 0, stream>>>(bfA, pooled, bfX, row_off, csr_src,
                                             batch, pw0, bl0, n_nodes, 0);
    sage_layer<<<sage_blk, NTS, 0, stream>>>(bfB, pooled, bfA, row_off, csr_src,
                                             batch, pw, bl, n_nodes, 0);
    sage_layer<<<sage_blk, NTS, 0, stream>>>(bfA, pooled, bfB, row_off, csr_src,
                                             batch, pw, bl, n_nodes, 0);
    sage_layer<<<sage_blk, NTS, 0, stream>>>(bfB, pooled, bfA, row_off, csr_src,
                                             batch, pw, bl, n_nodes, 1);

    head<<<32, NT, 0, stream>>>((float*)d_out, pooled, W1, b1, W2, b2);
}